// Round 1
// baseline (109.045 us; speedup 1.0000x reference)
//
#include <hip/hip_runtime.h>

// GQA sliding-window causal flash attention, bf16 MFMA, v10.
// = v9 (trunc-pack bf16, 32-q groups, 1024 blocks, runtime masks) with the
// staging pipeline restructured (T14 async-STAGE + double-buffered LDS):
//   - Ksh/Vsh double-buffered -> ONE barrier per step (was 2). 10->5
//     barriers per block.
//   - K(t+1) global loads issue right after the fragment ds_reads (latency
//     hides under tile A); K commit + V(t+1) loads between tiles (V latency
//     hides under tile B); V commit after tile B. All prefetched loads are
//     consumed (packed) BEFORE the next __syncthreads(), so the compiler's
//     vmcnt(0)-before-barrier drain never waits on the prefetch.
//   - Peak added register pressure ~+8 VGPR (K floats die at mid-tile
//     commit before V floats go live) to stay under the 128-VGPR cap.
//
// Mask table (step t covers keys [q0-128+32t, ..+32), halves h0/h1):
//   tile A (rows q0+rr):    t=0: h0 col>rr, h1 full | t=1..3 full | t=4: h0 col<=rr, h1 dead
//   tile B (rows q0+16+rr): t=0: h0 dead, h1 col>rr | t=1..3 full | t=4: h0 full, h1 col<=rr
// q0<128: loop enters at t_start=(128-q0)/32; first executed block needs no
// lower mask (window start <= 0) -> same runtime masks valid (v8 verified).

constexpr int NKV = 8, QM = 4, WIN = 128, BATCH = 2, SEQ = 2048;
constexpr int QSTRIDE = 2048, KSTRIDE = 512, HD = 64;

typedef __attribute__((ext_vector_type(8))) __bf16 bf16x8;
typedef __attribute__((ext_vector_type(8))) short short8_t;
typedef __attribute__((ext_vector_type(4))) float f32x4;
typedef __attribute__((ext_vector_type(4))) unsigned int uint4_t;

// pack two f32 into bf16x2 by truncation: one v_perm_b32.
__device__ __forceinline__ unsigned pk2(float lo, float hi) {
    return __builtin_amdgcn_perm(__float_as_uint(hi), __float_as_uint(lo), 0x07060302u);
}
__device__ __forceinline__ short8_t pack8(float4 a, float4 b) {
    return __builtin_bit_cast(short8_t,
        (uint4_t){pk2(a.x, a.y), pk2(a.z, a.w), pk2(b.x, b.y), pk2(b.z, b.w)});
}
__device__ __forceinline__ short hi16(float f) {   // bf16 truncate -> ds_write_b16_d16_hi
    return (short)(__float_as_uint(f) >> 16);
}

__device__ __forceinline__ f32x4 mfma16(short8_t a, short8_t b, f32x4 c) {
    return __builtin_amdgcn_mfma_f32_16x16x32_bf16(
        __builtin_bit_cast(bf16x8, a), __builtin_bit_cast(bf16x8, b), c, 0, 0, 0);
}

// exp(s/8 - 8) == exp2(s*C1 + C0); shift-invariant softmax, overflow-proof here.
constexpr float C1f = 0.18033688011112042f;   // 0.125 * log2(e)
constexpr float C0f = -11.541560327111707f;   // -8 * log2(e)

__global__ __launch_bounds__(256, 4)
void swa_mfma10(const float* __restrict__ Q, const float* __restrict__ K,
                const float* __restrict__ V, float* __restrict__ O)
{
    __shared__ __align__(16) short Ksh[2][32][72];     // [buf][key][d]
    __shared__ __align__(16) short Vsh[2][64][40];     // [buf][d][key] (transposed)
    __shared__ __align__(16) short Psh[4][16][40];     // per-wave P scratch

    const int tid  = threadIdx.x;
    const int lane = tid & 63;
    const int w    = tid >> 6;      // wave = q_mult m
    const int col  = lane & 15;
    const int quad = lane >> 4;

    int blk = blockIdx.x;
    const int b   = blk & 1;
    const int kvh = (blk >> 1) & 7;
    const int qg  = blk >> 4;       // 64 groups of 32 queries
    const int q0  = qg * 32;
    const int h   = kvh * QM + w;

    // ---- Q A-fragments for tiles A,B: A[m=col][k=quad*8+j], two d-halves
    const float* QA = Q + ((size_t)(b * SEQ + q0 + col) * QSTRIDE + h * HD);
    const float* QB = QA + (size_t)16 * QSTRIDE;
    short8_t aqA0, aqA1, aqB0, aqB1;
    {
        float4 f0 = *(const float4*)(QA + quad * 8);
        float4 f1 = *(const float4*)(QA + quad * 8 + 4);
        float4 g0 = *(const float4*)(QA + 32 + quad * 8);
        float4 g1 = *(const float4*)(QA + 32 + quad * 8 + 4);
        aqA0 = pack8(f0, f1);
        aqA1 = pack8(g0, g1);
        f0 = *(const float4*)(QB + quad * 8);
        f1 = *(const float4*)(QB + quad * 8 + 4);
        g0 = *(const float4*)(QB + 32 + quad * 8);
        g1 = *(const float4*)(QB + 32 + quad * 8 + 4);
        aqB0 = pack8(f0, f1);
        aqB1 = pack8(g0, g1);
    }

    const float* Kb = K + ((size_t)b * SEQ * KSTRIDE + (size_t)kvh * HD);
    const float* Vb = V + ((size_t)b * SEQ * KSTRIDE + (size_t)kvh * HD);

    f32x4 oA0 = {0.f,0.f,0.f,0.f}, oA1 = oA0, oA2 = oA0, oA3 = oA0;
    f32x4 oB0 = oA0, oB1 = oA0, oB2 = oA0, oB3 = oA0;
    float liA[4] = {0.f,0.f,0.f,0.f}, liB[4] = {0.f,0.f,0.f,0.f};

    const int krow = tid >> 3, kseg = tid & 7;  // K stage: 32 rows x 8 segs
    const int vd = tid & 63, vkg = tid >> 6;    // V stage: 64 d x 4 key-groups

    // first valid step (uniform per block); kbase monotone -> no later skips
    const int t_start = (q0 >= WIN) ? 0 : ((WIN - q0) >> 5);

    // ---- prologue: stage step t_start into buffer 0
    {
        const int kbase = q0 - WIN + 32 * t_start;
        const float* s = Kb + (size_t)(kbase + krow) * KSTRIDE + kseg * 8;
        const float4 a = *(const float4*)s;
        const float4 c = *(const float4*)(s + 4);
        *(short8_t*)&Ksh[0][krow][kseg * 8] = pack8(a, c);
        const float* sv = Vb + (size_t)(kbase + vkg * 8) * KSTRIDE + vd;
        const float u0 = sv[0],         u1 = sv[KSTRIDE],   u2 = sv[2*KSTRIDE],
                    u3 = sv[3*KSTRIDE], u4 = sv[4*KSTRIDE], u5 = sv[5*KSTRIDE],
                    u6 = sv[6*KSTRIDE], u7 = sv[7*KSTRIDE];
        *(short8_t*)&Vsh[0][vd][vkg * 8] = __builtin_bit_cast(short8_t,
            (uint4_t){pk2(u0, u1), pk2(u2, u3), pk2(u4, u5), pk2(u6, u7)});
    }

    int cur = 0;
#pragma unroll 1
    for (int t = t_start; t < 5; ++t) {
        const int nkbase = q0 - WIN + 32 * t + 32;   // base of step t+1
        const bool pf = (t < 4);

        __syncthreads();   // staged tile in buf[cur] visible; buf[cur^1] free

        const short8_t b0lo = *(const short8_t*)&Ksh[cur][col][quad * 8];
        const short8_t b0hi = *(const short8_t*)&Ksh[cur][col][quad * 8 + 32];
        const short8_t b1lo = *(const short8_t*)&Ksh[cur][16 + col][quad * 8];
        const short8_t b1hi = *(const short8_t*)&Ksh[cur][16 + col][quad * 8 + 32];
        const short8_t vb0  = *(const short8_t*)&Vsh[cur][col][quad * 8];
        const short8_t vb1  = *(const short8_t*)&Vsh[cur][16 + col][quad * 8];
        const short8_t vb2  = *(const short8_t*)&Vsh[cur][32 + col][quad * 8];
        const short8_t vb3  = *(const short8_t*)&Vsh[cur][48 + col][quad * 8];

        // prefetch K(t+1) -> regs; HBM latency hides under tile A
        float4 nka = {0.f,0.f,0.f,0.f}, nkc = nka;
        if (pf) {
            const float* s = Kb + (size_t)(nkbase + krow) * KSTRIDE + kseg * 8;
            nka = *(const float4*)s;
            nkc = *(const float4*)(s + 4);
        }

        // ---- tile A (rows q0..q0+15)
        {
            f32x4 s0 = {0.f,0.f,0.f,0.f}, s1 = s0;
            s0 = mfma16(aqA0, b0lo, s0); s0 = mfma16(aqA1, b0hi, s0);
            if (t < 4) { s1 = mfma16(aqA0, b1lo, s1); s1 = mfma16(aqA1, b1hi, s1); }
#pragma unroll
            for (int r = 0; r < 4; ++r) {
                const int rr = quad * 4 + r;
                float a0 = fmaf(s0[r], C1f, C0f);
                float a1 = fmaf(s1[r], C1f, C0f);
                if (t == 0) a0 = (col > rr)  ? a0 : -1e30f;
                if (t == 4) { a0 = (col <= rr) ? a0 : -1e30f; a1 = -1e30f; }
                const float p0 = exp2f(a0);
                const float p1 = (t < 4) ? exp2f(a1) : 0.f;
                liA[r] += p0 + p1;
                Psh[w][rr][col]      = hi16(p0);   // ds_write_b16_d16_hi
                Psh[w][rr][16 + col] = hi16(p1);
            }
            const short8_t pa = *(const short8_t*)&Psh[w][col][quad * 8];
            oA0 = mfma16(pa, vb0, oA0); oA1 = mfma16(pa, vb1, oA1);
            oA2 = mfma16(pa, vb2, oA2); oA3 = mfma16(pa, vb3, oA3);
        }

        // mid: commit K(t+1) (frees its regs), issue V(t+1) loads -> hide under tile B
        float nu0 = 0.f, nu1 = 0.f, nu2 = 0.f, nu3 = 0.f,
              nu4 = 0.f, nu5 = 0.f, nu6 = 0.f, nu7 = 0.f;
        if (pf) {
            *(short8_t*)&Ksh[cur ^ 1][krow][kseg * 8] = pack8(nka, nkc);
            const float* sv = Vb + (size_t)(nkbase + vkg * 8) * KSTRIDE + vd;
            nu0 = sv[0];           nu1 = sv[KSTRIDE];     nu2 = sv[2*KSTRIDE];
            nu3 = sv[3*KSTRIDE];   nu4 = sv[4*KSTRIDE];   nu5 = sv[5*KSTRIDE];
            nu6 = sv[6*KSTRIDE];   nu7 = sv[7*KSTRIDE];
        }

        // ---- tile B (rows q0+16..q0+31)
        {
            f32x4 s0 = {0.f,0.f,0.f,0.f}, s1 = s0;
            if (t > 0) { s0 = mfma16(aqB0, b0lo, s0); s0 = mfma16(aqB1, b0hi, s0); }
            s1 = mfma16(aqB0, b1lo, s1); s1 = mfma16(aqB1, b1hi, s1);
#pragma unroll
            for (int r = 0; r < 4; ++r) {
                const int rr = quad * 4 + r;
                float a0 = fmaf(s0[r], C1f, C0f);
                float a1 = fmaf(s1[r], C1f, C0f);
                if (t == 0) a1 = (col > rr) ? a1 : -1e30f;
                if (t == 4) a1 = (col <= rr) ? a1 : -1e30f;
                const float p0 = (t > 0) ? exp2f(a0) : 0.f;
                const float p1 = exp2f(a1);
                liB[r] += p0 + p1;
                Psh[w][rr][col]      = hi16(p0);
                Psh[w][rr][16 + col] = hi16(p1);
            }
            const short8_t pa = *(const short8_t*)&Psh[w][col][quad * 8];
            oB0 = mfma16(pa, vb0, oB0); oB1 = mfma16(pa, vb1, oB1);
            oB2 = mfma16(pa, vb2, oB2); oB3 = mfma16(pa, vb3, oB3);
        }

        // commit V(t+1); pack consumes the loads -> vmcnt drains naturally
        // before the next __syncthreads (no barrier-drain penalty).
        if (pf) {
            *(short8_t*)&Vsh[cur ^ 1][vd][vkg * 8] = __builtin_bit_cast(short8_t,
                (uint4_t){pk2(nu0, nu1), pk2(nu2, nu3), pk2(nu4, nu5), pk2(nu6, nu7)});
        }
        cur ^= 1;
    }

    // ---- epilogue: reduce l across 16-lane col group, normalize, store
    float* OA = O + ((size_t)(b * SEQ + q0) * QSTRIDE + h * HD);
    float* OB = OA + (size_t)16 * QSTRIDE;
#pragma unroll
    for (int r = 0; r < 4; ++r) {
        float lA = liA[r], lB = liB[r];
        lA += __shfl_xor(lA, 1); lA += __shfl_xor(lA, 2);
        lA += __shfl_xor(lA, 4); lA += __shfl_xor(lA, 8);
        lB += __shfl_xor(lB, 1); lB += __shfl_xor(lB, 2);
        lB += __shfl_xor(lB, 4); lB += __shfl_xor(lB, 8);
        const float iA = 1.0f / lA, iB = 1.0f / lB;
        const size_t row = (size_t)(quad * 4 + r) * QSTRIDE;
        OA[row + col]      = oA0[r] * iA;
        OA[row + 16 + col] = oA1[r] * iA;
        OA[row + 32 + col] = oA2[r] * iA;
        OA[row + 48 + col] = oA3[r] * iA;
        OB[row + col]      = oB0[r] * iB;
        OB[row + 16 + col] = oB1[r] * iB;
        OB[row + 32 + col] = oB2[r] * iB;
        OB[row + 48 + col] = oB3[r] * iB;
    }
}

extern "C" void kernel_launch(void* const* d_in, const int* in_sizes, int n_in,
                              void* d_out, int out_size, void* d_ws, size_t ws_size,
                              hipStream_t stream) {
    const float* Q = (const float*)d_in[0];
    const float* K = (const float*)d_in[1];
    const float* V = (const float*)d_in[2];
    // d_in[3] = sinks: unused by the reference math.
    float* O = (float*)d_out;

    dim3 grid(BATCH * NKV * (SEQ / 32));  // 1024 blocks = 4/CU
    dim3 block(256);
    swa_mfma10<<<grid, block, 0, stream>>>(Q, K, V, O);
}

// Round 2
// 107.506 us; speedup vs baseline: 1.0143x; 1.0143x over previous
//
#include <hip/hip_runtime.h>

// GQA sliding-window causal flash attention, bf16 MFMA, v11.
// = v9 (trunc-pack bf16, 32-q groups, 1024 blocks, runtime masks) with:
//   - LDS double-buffered, staging code UNCHANGED from v9 (one compact
//     load->pack->ds_write region; no split live ranges like failed v10).
//     One barrier per step (was 2): barrier only publishes buf[cur] and
//     retires prior reads of buf[cur^1]; staging of t+1 then runs
//     concurrently with tile A/B compute (compiler free to interleave).
//   - T5: s_setprio(1) around MFMA clusters. 4 independent blocks/CU give
//     the CU scheduler waves at different phases to arbitrate.
// v10 lesson: do NOT split stage into issue-early/commit-late halves; the
// +16 live VGPRs under the 128-cap (launch_bounds 256,4) cost more than the
// latency they hid (TLP already covers it).
//
// Mask table (step t covers keys [q0-128+32t, ..+32), halves h0/h1):
//   tile A (rows q0+rr):    t=0: h0 col>rr, h1 full | t=1..3 full | t=4: h0 col<=rr, h1 dead
//   tile B (rows q0+16+rr): t=0: h0 dead, h1 col>rr | t=1..3 full | t=4: h0 full, h1 col<=rr
// q0<128: loop enters at t_start=(128-q0)/32; first executed block needs no
// lower mask (window start <= 0) -> same runtime masks valid (v8 verified).

constexpr int NKV = 8, QM = 4, WIN = 128, BATCH = 2, SEQ = 2048;
constexpr int QSTRIDE = 2048, KSTRIDE = 512, HD = 64;

typedef __attribute__((ext_vector_type(8))) __bf16 bf16x8;
typedef __attribute__((ext_vector_type(8))) short short8_t;
typedef __attribute__((ext_vector_type(4))) float f32x4;
typedef __attribute__((ext_vector_type(4))) unsigned int uint4_t;

// pack two f32 into bf16x2 by truncation: one v_perm_b32.
__device__ __forceinline__ unsigned pk2(float lo, float hi) {
    return __builtin_amdgcn_perm(__float_as_uint(hi), __float_as_uint(lo), 0x07060302u);
}
__device__ __forceinline__ short8_t pack8(float4 a, float4 b) {
    return __builtin_bit_cast(short8_t,
        (uint4_t){pk2(a.x, a.y), pk2(a.z, a.w), pk2(b.x, b.y), pk2(b.z, b.w)});
}
__device__ __forceinline__ short hi16(float f) {   // bf16 truncate -> ds_write_b16_d16_hi
    return (short)(__float_as_uint(f) >> 16);
}

__device__ __forceinline__ f32x4 mfma16(short8_t a, short8_t b, f32x4 c) {
    return __builtin_amdgcn_mfma_f32_16x16x32_bf16(
        __builtin_bit_cast(bf16x8, a), __builtin_bit_cast(bf16x8, b), c, 0, 0, 0);
}

// exp(s/8 - 8) == exp2(s*C1 + C0); shift-invariant softmax, overflow-proof here.
constexpr float C1f = 0.18033688011112042f;   // 0.125 * log2(e)
constexpr float C0f = -11.541560327111707f;   // -8 * log2(e)

__global__ __launch_bounds__(256, 4)
void swa_mfma11(const float* __restrict__ Q, const float* __restrict__ K,
                const float* __restrict__ V, float* __restrict__ O)
{
    __shared__ __align__(16) short Ksh[2][32][72];     // [buf][key][d]
    __shared__ __align__(16) short Vsh[2][64][40];     // [buf][d][key] (transposed)
    __shared__ __align__(16) short Psh[4][16][40];     // per-wave P scratch

    const int tid  = threadIdx.x;
    const int lane = tid & 63;
    const int w    = tid >> 6;      // wave = q_mult m
    const int col  = lane & 15;
    const int quad = lane >> 4;

    int blk = blockIdx.x;
    const int b   = blk & 1;
    const int kvh = (blk >> 1) & 7;
    const int qg  = blk >> 4;       // 64 groups of 32 queries
    const int q0  = qg * 32;
    const int h   = kvh * QM + w;

    // ---- Q A-fragments for tiles A,B: A[m=col][k=quad*8+j], two d-halves
    const float* QA = Q + ((size_t)(b * SEQ + q0 + col) * QSTRIDE + h * HD);
    const float* QB = QA + (size_t)16 * QSTRIDE;
    short8_t aqA0, aqA1, aqB0, aqB1;
    {
        float4 f0 = *(const float4*)(QA + quad * 8);
        float4 f1 = *(const float4*)(QA + quad * 8 + 4);
        float4 g0 = *(const float4*)(QA + 32 + quad * 8);
        float4 g1 = *(const float4*)(QA + 32 + quad * 8 + 4);
        aqA0 = pack8(f0, f1);
        aqA1 = pack8(g0, g1);
        f0 = *(const float4*)(QB + quad * 8);
        f1 = *(const float4*)(QB + quad * 8 + 4);
        g0 = *(const float4*)(QB + 32 + quad * 8);
        g1 = *(const float4*)(QB + 32 + quad * 8 + 4);
        aqB0 = pack8(f0, f1);
        aqB1 = pack8(g0, g1);
    }

    const float* Kb = K + ((size_t)b * SEQ * KSTRIDE + (size_t)kvh * HD);
    const float* Vb = V + ((size_t)b * SEQ * KSTRIDE + (size_t)kvh * HD);

    f32x4 oA0 = {0.f,0.f,0.f,0.f}, oA1 = oA0, oA2 = oA0, oA3 = oA0;
    f32x4 oB0 = oA0, oB1 = oA0, oB2 = oA0, oB3 = oA0;
    float liA[4] = {0.f,0.f,0.f,0.f}, liB[4] = {0.f,0.f,0.f,0.f};

    const int krow = tid >> 3, kseg = tid & 7;  // K stage: 32 rows x 8 segs
    const int vd = tid & 63, vkg = tid >> 6;    // V stage: 64 d x 4 key-groups

    // first valid step (uniform per block); kbase monotone -> no later skips
    const int t_start = (q0 >= WIN) ? 0 : ((WIN - q0) >> 5);

    // ---- prologue: stage step t_start into buffer 0 (v9 staging code)
    {
        const int kbase = q0 - WIN + 32 * t_start;
        const float* s = Kb + (size_t)(kbase + krow) * KSTRIDE + kseg * 8;
        const float4 a = *(const float4*)s;
        const float4 c = *(const float4*)(s + 4);
        *(short8_t*)&Ksh[0][krow][kseg * 8] = pack8(a, c);
        const float* sv = Vb + (size_t)(kbase + vkg * 8) * KSTRIDE + vd;
        const float u0 = sv[0],         u1 = sv[KSTRIDE],   u2 = sv[2*KSTRIDE],
                    u3 = sv[3*KSTRIDE], u4 = sv[4*KSTRIDE], u5 = sv[5*KSTRIDE],
                    u6 = sv[6*KSTRIDE], u7 = sv[7*KSTRIDE];
        *(short8_t*)&Vsh[0][vd][vkg * 8] = __builtin_bit_cast(short8_t,
            (uint4_t){pk2(u0, u1), pk2(u2, u3), pk2(u4, u5), pk2(u6, u7)});
    }

    int cur = 0;
#pragma unroll 1
    for (int t = t_start; t < 5; ++t) {
        __syncthreads();   // buf[cur] staged+visible; prior reads of buf[cur^1] retired

        // fragment reads from current buffer (ds_reads issue first)
        const short8_t b0lo = *(const short8_t*)&Ksh[cur][col][quad * 8];
        const short8_t b0hi = *(const short8_t*)&Ksh[cur][col][quad * 8 + 32];
        const short8_t b1lo = *(const short8_t*)&Ksh[cur][16 + col][quad * 8];
        const short8_t b1hi = *(const short8_t*)&Ksh[cur][16 + col][quad * 8 + 32];
        const short8_t vb0  = *(const short8_t*)&Vsh[cur][col][quad * 8];
        const short8_t vb1  = *(const short8_t*)&Vsh[cur][16 + col][quad * 8];
        const short8_t vb2  = *(const short8_t*)&Vsh[cur][32 + col][quad * 8];
        const short8_t vb3  = *(const short8_t*)&Vsh[cur][48 + col][quad * 8];

        // stage t+1 into buf[cur^1]: compact v9 region, free to interleave
        // with the compute below (no barrier until next loop top).
        if (t < 4) {
            const int nkbase = q0 - WIN + 32 * t + 32;
            const float* s = Kb + (size_t)(nkbase + krow) * KSTRIDE + kseg * 8;
            const float4 a = *(const float4*)s;
            const float4 c = *(const float4*)(s + 4);
            *(short8_t*)&Ksh[cur ^ 1][krow][kseg * 8] = pack8(a, c);
            const float* sv = Vb + (size_t)(nkbase + vkg * 8) * KSTRIDE + vd;
            const float u0 = sv[0],         u1 = sv[KSTRIDE],   u2 = sv[2*KSTRIDE],
                        u3 = sv[3*KSTRIDE], u4 = sv[4*KSTRIDE], u5 = sv[5*KSTRIDE],
                        u6 = sv[6*KSTRIDE], u7 = sv[7*KSTRIDE];
            *(short8_t*)&Vsh[cur ^ 1][vd][vkg * 8] = __builtin_bit_cast(short8_t,
                (uint4_t){pk2(u0, u1), pk2(u2, u3), pk2(u4, u5), pk2(u6, u7)});
        }

        // ---- tile A (rows q0..q0+15)
        {
            f32x4 s0 = {0.f,0.f,0.f,0.f}, s1 = s0;
            __builtin_amdgcn_s_setprio(1);
            s0 = mfma16(aqA0, b0lo, s0); s0 = mfma16(aqA1, b0hi, s0);
            if (t < 4) { s1 = mfma16(aqA0, b1lo, s1); s1 = mfma16(aqA1, b1hi, s1); }
            __builtin_amdgcn_s_setprio(0);
#pragma unroll
            for (int r = 0; r < 4; ++r) {
                const int rr = quad * 4 + r;
                float a0 = fmaf(s0[r], C1f, C0f);
                float a1 = fmaf(s1[r], C1f, C0f);
                if (t == 0) a0 = (col > rr)  ? a0 : -1e30f;
                if (t == 4) { a0 = (col <= rr) ? a0 : -1e30f; a1 = -1e30f; }
                const float p0 = exp2f(a0);
                const float p1 = (t < 4) ? exp2f(a1) : 0.f;
                liA[r] += p0 + p1;
                Psh[w][rr][col]      = hi16(p0);   // ds_write_b16_d16_hi
                Psh[w][rr][16 + col] = hi16(p1);
            }
            const short8_t pa = *(const short8_t*)&Psh[w][col][quad * 8];
            __builtin_amdgcn_s_setprio(1);
            oA0 = mfma16(pa, vb0, oA0); oA1 = mfma16(pa, vb1, oA1);
            oA2 = mfma16(pa, vb2, oA2); oA3 = mfma16(pa, vb3, oA3);
            __builtin_amdgcn_s_setprio(0);
        }

        // ---- tile B (rows q0+16..q0+31)
        {
            f32x4 s0 = {0.f,0.f,0.f,0.f}, s1 = s0;
            __builtin_amdgcn_s_setprio(1);
            if (t > 0) { s0 = mfma16(aqB0, b0lo, s0); s0 = mfma16(aqB1, b0hi, s0); }
            s1 = mfma16(aqB0, b1lo, s1); s1 = mfma16(aqB1, b1hi, s1);
            __builtin_amdgcn_s_setprio(0);
#pragma unroll
            for (int r = 0; r < 4; ++r) {
                const int rr = quad * 4 + r;
                float a0 = fmaf(s0[r], C1f, C0f);
                float a1 = fmaf(s1[r], C1f, C0f);
                if (t == 0) a1 = (col > rr) ? a1 : -1e30f;
                if (t == 4) a1 = (col <= rr) ? a1 : -1e30f;
                const float p0 = (t > 0) ? exp2f(a0) : 0.f;
                const float p1 = exp2f(a1);
                liB[r] += p0 + p1;
                Psh[w][rr][col]      = hi16(p0);
                Psh[w][rr][16 + col] = hi16(p1);
            }
            const short8_t pa = *(const short8_t*)&Psh[w][col][quad * 8];
            __builtin_amdgcn_s_setprio(1);
            oB0 = mfma16(pa, vb0, oB0); oB1 = mfma16(pa, vb1, oB1);
            oB2 = mfma16(pa, vb2, oB2); oB3 = mfma16(pa, vb3, oB3);
            __builtin_amdgcn_s_setprio(0);
        }
        cur ^= 1;
    }

    // ---- epilogue: reduce l across 16-lane col group, normalize, store
    float* OA = O + ((size_t)(b * SEQ + q0) * QSTRIDE + h * HD);
    float* OB = OA + (size_t)16 * QSTRIDE;
#pragma unroll
    for (int r = 0; r < 4; ++r) {
        float lA = liA[r], lB = liB[r];
        lA += __shfl_xor(lA, 1); lA += __shfl_xor(lA, 2);
        lA += __shfl_xor(lA, 4); lA += __shfl_xor(lA, 8);
        lB += __shfl_xor(lB, 1); lB += __shfl_xor(lB, 2);
        lB += __shfl_xor(lB, 4); lB += __shfl_xor(lB, 8);
        const float iA = 1.0f / lA, iB = 1.0f / lB;
        const size_t row = (size_t)(quad * 4 + r) * QSTRIDE;
        OA[row + col]      = oA0[r] * iA;
        OA[row + 16 + col] = oA1[r] * iA;
        OA[row + 32 + col] = oA2[r] * iA;
        OA[row + 48 + col] = oA3[r] * iA;
        OB[row + col]      = oB0[r] * iB;
        OB[row + 16 + col] = oB1[r] * iB;
        OB[row + 32 + col] = oB2[r] * iB;
        OB[row + 48 + col] = oB3[r] * iB;
    }
}

extern "C" void kernel_launch(void* const* d_in, const int* in_sizes, int n_in,
                              void* d_out, int out_size, void* d_ws, size_t ws_size,
                              hipStream_t stream) {
    const float* Q = (const float*)d_in[0];
    const float* K = (const float*)d_in[1];
    const float* V = (const float*)d_in[2];
    // d_in[3] = sinks: unused by the reference math.
    float* O = (float*)d_out;

    dim3 grid(BATCH * NKV * (SEQ / 32));  // 1024 blocks = 4/CU
    dim3 block(256);
    swa_mfma11<<<grid, block, 0, stream>>>(Q, K, V, O);
}

// Round 4
// 104.884 us; speedup vs baseline: 1.0397x; 1.0250x over previous
//
#include <hip/hip_runtime.h>

// GQA sliding-window causal flash attention, bf16 MFMA, v12b.
// = v9 EXACTLY (best measured: 32-q groups, 1024 blocks, single-buffer LDS,
// 2 barriers/step, runtime masks, trunc-pack bf16) plus ONE isolated change:
// non-temporal hints on the zero-reuse streams (Q loads, O stores) so they
// don't thrash the per-XCD L2 that carries the 5x K/V window reuse.
// v12 build fix: __builtin_nontemporal_load requires ext_vector/scalar
// pointer types -- use our own f32x4 (ext_vector_type(4) float), not the
// HIP float4 class.
//   - blocks sharing (b,kvh) land on one XCD (blk stride 16); their K+V
//     slice is 2 MB/XCD and fits the 4 MB L2, but Q/O stream 8.4 MB/XCD
//     through the same L2 with zero reuse -> evicts K/V between uses.
//   - K/V staging loads stay cached (they ARE the reuse).
// v10/v11 lesson: pipeline restructures (split stage, dbuf+1-barrier,
// setprio) all regress -- inter-block TLP already hides staging latency;
// do not touch the v9 schedule.
//
// Mask table (step t covers keys [q0-128+32t, ..+32), halves h0/h1):
//   tile A (rows q0+rr):    t=0: h0 col>rr, h1 full | t=1..3 full | t=4: h0 col<=rr, h1 dead
//   tile B (rows q0+16+rr): t=0: h0 dead, h1 col>rr | t=1..3 full | t=4: h0 full, h1 col<=rr
// q0<128: loop enters at t_start=(128-q0)/32; first executed block needs no
// lower mask (window start <= 0) -> same runtime masks valid (v8 verified).

constexpr int NKV = 8, QM = 4, WIN = 128, BATCH = 2, SEQ = 2048;
constexpr int QSTRIDE = 2048, KSTRIDE = 512, HD = 64;

typedef __attribute__((ext_vector_type(8))) __bf16 bf16x8;
typedef __attribute__((ext_vector_type(8))) short short8_t;
typedef __attribute__((ext_vector_type(4))) float f32x4;
typedef __attribute__((ext_vector_type(4))) unsigned int uint4_t;

// pack two f32 into bf16x2 by truncation: one v_perm_b32.
__device__ __forceinline__ unsigned pk2(float lo, float hi) {
    return __builtin_amdgcn_perm(__float_as_uint(hi), __float_as_uint(lo), 0x07060302u);
}
__device__ __forceinline__ short8_t pack8(float4 a, float4 b) {
    return __builtin_bit_cast(short8_t,
        (uint4_t){pk2(a.x, a.y), pk2(a.z, a.w), pk2(b.x, b.y), pk2(b.z, b.w)});
}
__device__ __forceinline__ short8_t pack8v(f32x4 a, f32x4 b) {
    return __builtin_bit_cast(short8_t,
        (uint4_t){pk2(a[0], a[1]), pk2(a[2], a[3]), pk2(b[0], b[1]), pk2(b[2], b[3])});
}
__device__ __forceinline__ short hi16(float f) {   // bf16 truncate, folds into b16_d16_hi store
    return (short)(__float_as_uint(f) >> 16);
}

__device__ __forceinline__ f32x4 mfma16(short8_t a, short8_t b, f32x4 c) {
    return __builtin_amdgcn_mfma_f32_16x16x32_bf16(
        __builtin_bit_cast(bf16x8, a), __builtin_bit_cast(bf16x8, b), c, 0, 0, 0);
}

// non-temporal float4 load (ext_vector type -- builtin-legal): nt-flagged
// global_load_dwordx4, low L2 retention for zero-reuse streams.
__device__ __forceinline__ f32x4 ntload4(const float* p) {
    return __builtin_nontemporal_load((const f32x4*)p);
}

// exp(s/8 - 8) == exp2(s*C1 + C0); shift-invariant softmax, overflow-proof here.
constexpr float C1f = 0.18033688011112042f;   // 0.125 * log2(e)
constexpr float C0f = -11.541560327111707f;   // -8 * log2(e)

__global__ __launch_bounds__(256, 4)
void swa_mfma12b(const float* __restrict__ Q, const float* __restrict__ K,
                 const float* __restrict__ V, float* __restrict__ O)
{
    __shared__ __align__(16) short Ksh[32][72];     // [key][d]
    __shared__ __align__(16) short Vsh[64][40];     // [d][key] (transposed)
    __shared__ __align__(16) short Psh[4][16][40];  // per-wave P scratch

    const int tid  = threadIdx.x;
    const int lane = tid & 63;
    const int w    = tid >> 6;      // wave = q_mult m
    const int col  = lane & 15;
    const int quad = lane >> 4;

    int blk = blockIdx.x;
    const int b   = blk & 1;
    const int kvh = (blk >> 1) & 7;
    const int qg  = blk >> 4;       // 64 groups of 32 queries
    const int q0  = qg * 32;
    const int h   = kvh * QM + w;

    // ---- Q A-fragments for tiles A,B: A[m=col][k=quad*8+j], two d-halves
    const float* QA = Q + ((size_t)(b * SEQ + q0 + col) * QSTRIDE + h * HD);
    const float* QB = QA + (size_t)16 * QSTRIDE;
    short8_t aqA0, aqA1, aqB0, aqB1;
    {
        f32x4 f0 = ntload4(QA + quad * 8);
        f32x4 f1 = ntload4(QA + quad * 8 + 4);
        f32x4 g0 = ntload4(QA + 32 + quad * 8);
        f32x4 g1 = ntload4(QA + 32 + quad * 8 + 4);
        aqA0 = pack8v(f0, f1);
        aqA1 = pack8v(g0, g1);
        f0 = ntload4(QB + quad * 8);
        f1 = ntload4(QB + quad * 8 + 4);
        g0 = ntload4(QB + 32 + quad * 8);
        g1 = ntload4(QB + 32 + quad * 8 + 4);
        aqB0 = pack8v(f0, f1);
        aqB1 = pack8v(g0, g1);
    }

    const float* Kb = K + ((size_t)b * SEQ * KSTRIDE + (size_t)kvh * HD);
    const float* Vb = V + ((size_t)b * SEQ * KSTRIDE + (size_t)kvh * HD);

    f32x4 oA0 = {0.f,0.f,0.f,0.f}, oA1 = oA0, oA2 = oA0, oA3 = oA0;
    f32x4 oB0 = oA0, oB1 = oA0, oB2 = oA0, oB3 = oA0;
    float liA[4] = {0.f,0.f,0.f,0.f}, liB[4] = {0.f,0.f,0.f,0.f};

    const int krow = tid >> 3, kseg = tid & 7;  // K stage: 32 rows x 8 segs
    const int vd = tid & 63, vkg = tid >> 6;    // V stage: 64 d x 4 key-groups

    // first valid step (uniform per block); kbase monotone -> no later skips
    const int t_start = (q0 >= WIN) ? 0 : ((WIN - q0) >> 5);

#pragma unroll 1
    for (int t = t_start; t < 5; ++t) {
        const int kbase = q0 - WIN + 32 * t;

        __syncthreads();   // previous step's compute reads done
        {   // K stage: 32B/thread coalesced, trunc-pack (4 v_perm)
            const float* s = Kb + (size_t)(kbase + krow) * KSTRIDE + kseg * 8;
            const float4 a = *(const float4*)s;
            const float4 c = *(const float4*)(s + 4);
            *(short8_t*)&Ksh[krow][kseg * 8] = pack8(a, c);
        }
        {   // V stage transposed: lane=d coalesced, 8 keys/thread, trunc-pack
            const float* sv = Vb + (size_t)(kbase + vkg * 8) * KSTRIDE + vd;
            const float u0 = sv[0],           u1 = sv[KSTRIDE],     u2 = sv[2*KSTRIDE],
                        u3 = sv[3*KSTRIDE],   u4 = sv[4*KSTRIDE],   u5 = sv[5*KSTRIDE],
                        u6 = sv[6*KSTRIDE],   u7 = sv[7*KSTRIDE];
            *(short8_t*)&Vsh[vd][vkg * 8] = __builtin_bit_cast(short8_t,
                (uint4_t){pk2(u0, u1), pk2(u2, u3), pk2(u4, u5), pk2(u6, u7)});
        }
        __syncthreads();   // staged tile visible

        const short8_t b0lo = *(const short8_t*)&Ksh[col][quad * 8];
        const short8_t b0hi = *(const short8_t*)&Ksh[col][quad * 8 + 32];
        const short8_t b1lo = *(const short8_t*)&Ksh[16 + col][quad * 8];
        const short8_t b1hi = *(const short8_t*)&Ksh[16 + col][quad * 8 + 32];
        const short8_t vb0  = *(const short8_t*)&Vsh[col][quad * 8];
        const short8_t vb1  = *(const short8_t*)&Vsh[16 + col][quad * 8];
        const short8_t vb2  = *(const short8_t*)&Vsh[32 + col][quad * 8];
        const short8_t vb3  = *(const short8_t*)&Vsh[48 + col][quad * 8];

        // ---- tile A (rows q0..q0+15)
        {
            f32x4 s0 = {0.f,0.f,0.f,0.f}, s1 = s0;
            s0 = mfma16(aqA0, b0lo, s0); s0 = mfma16(aqA1, b0hi, s0);
            if (t < 4) { s1 = mfma16(aqA0, b1lo, s1); s1 = mfma16(aqA1, b1hi, s1); }
#pragma unroll
            for (int r = 0; r < 4; ++r) {
                const int rr = quad * 4 + r;
                float a0 = fmaf(s0[r], C1f, C0f);
                float a1 = fmaf(s1[r], C1f, C0f);
                if (t == 0) a0 = (col > rr)  ? a0 : -1e30f;
                if (t == 4) { a0 = (col <= rr) ? a0 : -1e30f; a1 = -1e30f; }
                const float p0 = exp2f(a0);
                const float p1 = (t < 4) ? exp2f(a1) : 0.f;
                liA[r] += p0 + p1;
                Psh[w][rr][col]      = hi16(p0);   // ds_write_b16_d16_hi
                Psh[w][rr][16 + col] = hi16(p1);
            }
            const short8_t pa = *(const short8_t*)&Psh[w][col][quad * 8];
            oA0 = mfma16(pa, vb0, oA0); oA1 = mfma16(pa, vb1, oA1);
            oA2 = mfma16(pa, vb2, oA2); oA3 = mfma16(pa, vb3, oA3);
        }

        // ---- tile B (rows q0+16..q0+31)
        {
            f32x4 s0 = {0.f,0.f,0.f,0.f}, s1 = s0;
            if (t > 0) { s0 = mfma16(aqB0, b0lo, s0); s0 = mfma16(aqB1, b0hi, s0); }
            s1 = mfma16(aqB0, b1lo, s1); s1 = mfma16(aqB1, b1hi, s1);
#pragma unroll
            for (int r = 0; r < 4; ++r) {
                const int rr = quad * 4 + r;
                float a0 = fmaf(s0[r], C1f, C0f);
                float a1 = fmaf(s1[r], C1f, C0f);
                if (t == 0) a1 = (col > rr) ? a1 : -1e30f;
                if (t == 4) a1 = (col <= rr) ? a1 : -1e30f;
                const float p0 = (t > 0) ? exp2f(a0) : 0.f;
                const float p1 = exp2f(a1);
                liB[r] += p0 + p1;
                Psh[w][rr][col]      = hi16(p0);
                Psh[w][rr][16 + col] = hi16(p1);
            }
            const short8_t pa = *(const short8_t*)&Psh[w][col][quad * 8];
            oB0 = mfma16(pa, vb0, oB0); oB1 = mfma16(pa, vb1, oB1);
            oB2 = mfma16(pa, vb2, oB2); oB3 = mfma16(pa, vb3, oB3);
        }
    }

    // ---- epilogue: reduce l across 16-lane col group, normalize, store (nt)
    float* OA = O + ((size_t)(b * SEQ + q0) * QSTRIDE + h * HD);
    float* OB = OA + (size_t)16 * QSTRIDE;
#pragma unroll
    for (int r = 0; r < 4; ++r) {
        float lA = liA[r], lB = liB[r];
        lA += __shfl_xor(lA, 1); lA += __shfl_xor(lA, 2);
        lA += __shfl_xor(lA, 4); lA += __shfl_xor(lA, 8);
        lB += __shfl_xor(lB, 1); lB += __shfl_xor(lB, 2);
        lB += __shfl_xor(lB, 4); lB += __shfl_xor(lB, 8);
        const float iA = 1.0f / lA, iB = 1.0f / lB;
        const size_t row = (size_t)(quad * 4 + r) * QSTRIDE;
        __builtin_nontemporal_store(oA0[r] * iA, &OA[row + col]);
        __builtin_nontemporal_store(oA1[r] * iA, &OA[row + 16 + col]);
        __builtin_nontemporal_store(oA2[r] * iA, &OA[row + 32 + col]);
        __builtin_nontemporal_store(oA3[r] * iA, &OA[row + 48 + col]);
        __builtin_nontemporal_store(oB0[r] * iB, &OB[row + col]);
        __builtin_nontemporal_store(oB1[r] * iB, &OB[row + 16 + col]);
        __builtin_nontemporal_store(oB2[r] * iB, &OB[row + 32 + col]);
        __builtin_nontemporal_store(oB3[r] * iB, &OB[row + 48 + col]);
    }
}

extern "C" void kernel_launch(void* const* d_in, const int* in_sizes, int n_in,
                              void* d_out, int out_size, void* d_ws, size_t ws_size,
                              hipStream_t stream) {
    const float* Q = (const float*)d_in[0];
    const float* K = (const float*)d_in[1];
    const float* V = (const float*)d_in[2];
    // d_in[3] = sinks: unused by the reference math.
    float* O = (float*)d_out;

    dim3 grid(BATCH * NKV * (SEQ / 32));  // 1024 blocks = 4/CU
    dim3 block(256);
    swa_mfma12b<<<grid, block, 0, stream>>>(Q, K, V, O);
}